// Round 4
// baseline (720.965 us; speedup 1.0000x reference)
//
#include <hip/hip_runtime.h>
#include <math.h>

#define B_ 16
#define H_ 224
#define W_ 224
#define HP_ 226
#define WP_ 226
#define COUT_ 64
#define NPIX_ (B_ * H_ * W_)      /* 802816 */
#define NPAD_ (B_ * HP_ * WP_)    /* 817216 */
#define P_ 8                      /* pixels per k1 thread */
#define K1BLK_ (NPIX_ / 256)      /* 3136: 8 ch/thread, 8 px/thread */
#define K3BLK_ (NPIX_ * 4 / 256)  /* 12544: 16 ch/thread */
#define MAXNORM_ 0.999f
#define MINN_ 1e-7f
#define TCL_ (1.0f - 1e-5f)
#define LCLAMP_ 3.8002012f        /* atanh(0.999) */
#define BN_EPS_ 1e-5f
#define NF_ ((float)NPIX_)

typedef float v4f __attribute__((ext_vector_type(4)));

__device__ __forceinline__ float hadd(v4f v) { return (v.x + v.y) + (v.z + v.w); }
__device__ __forceinline__ v4f vshfl_xor(v4f v, int m) {
  v4f r;
  r.x = __shfl_xor(v.x, m, 64); r.y = __shfl_xor(v.y, m, 64);
  r.z = __shfl_xor(v.z, m, 64); r.w = __shfl_xor(v.w, m, 64);
  return r;
}
__device__ __forceinline__ v4f vmax0(v4f v) {
  v.x = fmaxf(v.x, 0.f); v.y = fmaxf(v.y, 0.f);
  v.z = fmaxf(v.z, 0.f); v.w = fmaxf(v.w, 0.f);
  return v;
}

// ---------------------------------------------------------------------------
// K0: x (NCHW f32) -> u0p (padded NHWC4): u0 = logmap0(projx(x)), zero halo.
// ws is re-poisoned every launch, so the halo must be rewritten every call.
// ---------------------------------------------------------------------------
__global__ void __launch_bounds__(256)
k0_transform(const float* __restrict__ x, float4* __restrict__ u0p) {
  int idx = blockIdx.x * 256 + threadIdx.x;
  if (idx >= NPAD_) return;
  int b = idx / (HP_ * WP_);
  int r = idx % (HP_ * WP_);
  int yp = r / WP_, xp = r % WP_;
  float4 o = make_float4(0.f, 0.f, 0.f, 0.f);
  if (yp >= 1 && yp <= H_ && xp >= 1 && xp <= W_) {
    const float* xb = x + (size_t)b * (3 * H_ * W_) + (size_t)(yp - 1) * W_ + (xp - 1);
    float v0 = xb[0];
    float v1 = xb[H_ * W_];
    float v2 = xb[2 * H_ * W_];
    float n = sqrtf(fmaf(v0, v0, fmaf(v1, v1, v2 * v2)));
    float s = fminf(1.0f, MAXNORM_ / fmaxf(n, MINN_));
    float p0 = v0 * s, p1 = v1 * s, p2 = v2 * s;
    float np_ = fmaxf(sqrtf(fmaf(p0, p0, fmaf(p1, p1, p2 * p2))), MINN_);
    float t = fminf(np_, TCL_);
    float f = atanhf(t) / np_;
    o.x = p0 * f; o.y = p1 * f; o.z = p2 * f;
  }
  u0p[idx] = o;
}

// ---------------------------------------------------------------------------
// conv16: 16 output channels (quarter qt) of one pixel; 4 lanes/pixel.
// Weight v4f index = tap*48 + cin*16 + qt*4 + i — one 4-lane group's loads
// span a single 64B line (L1 broadcast). Norm over 64 ch = 2 shfl_xor.
// Fused logmap0(projx(expmap0(t))) == t * min(1, L/||t||).
// ---------------------------------------------------------------------------
__device__ __forceinline__ void conv16_clamp(const float4* __restrict__ u0p,
                                             const v4f* __restrict__ w4,
                                             const v4f* __restrict__ b4,
                                             int pix, int qt,
                                             v4f& a0, v4f& a1, v4f& a2, v4f& a3) {
  int b = pix / (H_ * W_);
  int r = pix % (H_ * W_);
  int y = r / W_, x = r % W_;
  const float4* base = u0p + ((size_t)b * HP_ + y) * WP_ + x;
  const v4f* wq = w4 + qt * 4;
  a0 = b4[qt * 4 + 0]; a1 = b4[qt * 4 + 1]; a2 = b4[qt * 4 + 2]; a3 = b4[qt * 4 + 3];
#define TAP(t) { float4 in = base[((t) / 3) * WP_ + ((t) % 3)];                      \
    const v4f* wp = wq + (t) * 48;                                                   \
    a0 += in.x * wp[0];  a1 += in.x * wp[1];  a2 += in.x * wp[2];  a3 += in.x * wp[3];   \
    a0 += in.y * wp[16]; a1 += in.y * wp[17]; a2 += in.y * wp[18]; a3 += in.y * wp[19];  \
    a0 += in.z * wp[32]; a1 += in.z * wp[33]; a2 += in.z * wp[34]; a3 += in.z * wp[35]; }
  TAP(0) TAP(1) TAP(2) TAP(3) TAP(4) TAP(5) TAP(6) TAP(7) TAP(8)
#undef TAP
  float p = hadd(a0 * a0 + a1 * a1 + a2 * a2 + a3 * a3);
  p += __shfl_xor(p, 1, 64);
  p += __shfl_xor(p, 2, 64);
  float n = sqrtf(p);
  float sc = (n > LCLAMP_) ? (LCLAMP_ / n) : 1.0f;
  a0 *= sc; a1 *= sc; a2 *= sc; a3 *= sc;
}

// ---------------------------------------------------------------------------
// conv8: 8 channels (octant) of one pixel; 8 lanes/pixel. Norm = 3 shfl_xor.
// ---------------------------------------------------------------------------
__device__ __forceinline__ void conv8_clamp(const float4* __restrict__ u0p,
                                            const v4f* __restrict__ w4,
                                            const v4f* __restrict__ b4,
                                            int pix, int oct, v4f& a0, v4f& a1) {
  int b = pix / (H_ * W_);
  int r = pix % (H_ * W_);
  int y = r / W_, x = r % W_;
  const float4* base = u0p + ((size_t)b * HP_ + y) * WP_ + x;
  const v4f* wo = w4 + oct * 2;
  a0 = b4[oct * 2 + 0]; a1 = b4[oct * 2 + 1];
#define TAP(t) { float4 in = base[((t) / 3) * WP_ + ((t) % 3)];   \
    const v4f* wp = wo + (t) * 48;                                 \
    a0 += in.x * wp[0];  a1 += in.x * wp[1];                       \
    a0 += in.y * wp[16]; a1 += in.y * wp[17];                      \
    a0 += in.z * wp[32]; a1 += in.z * wp[33]; }
  TAP(0) TAP(1) TAP(2) TAP(3) TAP(4) TAP(5) TAP(6) TAP(7) TAP(8)
#undef TAP
  float p = hadd(a0 * a0 + a1 * a1);
  p += __shfl_xor(p, 1, 64);
  p += __shfl_xor(p, 2, 64);
  p += __shfl_xor(p, 4, 64);
  float n = sqrtf(p);
  float sc = (n > LCLAMP_) ? (LCLAMP_ / n) : 1.0f;
  a0 *= sc; a1 *= sc;
}

// ---------------------------------------------------------------------------
// K1: per-thread 8-channel sum/sumsq over 8 pixels (no cross-lane in loop),
// one 3-mask fold at the end, block-combine in LDS -> 128-float partial row.
// Live state ~45 VGPRs: fits under the allocator's stubborn ~56-VGPR budget
// (R2/R3: launch_bounds did NOT lift it; 64-ch/thread spilled 336 B/thread).
// ---------------------------------------------------------------------------
__global__ void __launch_bounds__(256)
k1_stats(const float4* __restrict__ u0p, const float* __restrict__ wgt,
         const float* __restrict__ bias, float* __restrict__ partials) {
  int g = blockIdx.x * 256 + threadIdx.x;
  int oct = g & 7;
  int pg = g >> 3;
  const v4f* w4 = (const v4f*)wgt;
  const v4f* b4 = (const v4f*)bias;
  v4f s0 = (v4f)0.f, s1 = (v4f)0.f, q0 = (v4f)0.f, q1 = (v4f)0.f;
  for (int k = 0; k < P_; k++) {
    v4f a0, a1;
    conv8_clamp(u0p, w4, b4, pg * P_ + k, oct, a0, a1);
    s0 += a0; s1 += a1;
    q0 += a0 * a0; q1 += a1 * a1;
  }
  // combine the 8 lanes holding the same octant (masks 8,16,32)
  s0 += vshfl_xor(s0, 8);  s1 += vshfl_xor(s1, 8);
  q0 += vshfl_xor(q0, 8);  q1 += vshfl_xor(q1, 8);
  s0 += vshfl_xor(s0, 16); s1 += vshfl_xor(s1, 16);
  q0 += vshfl_xor(q0, 16); q1 += vshfl_xor(q1, 16);
  s0 += vshfl_xor(s0, 32); s1 += vshfl_xor(s1, 32);
  q0 += vshfl_xor(q0, 32); q1 += vshfl_xor(q1, 32);
  __shared__ v4f red[128];  // 4 waves x (16 sum-v4f + 16 sumsq-v4f)
  int lane = threadIdx.x & 63, wid = threadIdx.x >> 6;
  if (lane < 8) {
    red[wid * 32 + lane * 2 + 0] = s0;
    red[wid * 32 + lane * 2 + 1] = s1;
    red[wid * 32 + 16 + lane * 2 + 0] = q0;
    red[wid * 32 + 16 + lane * 2 + 1] = q1;
  }
  __syncthreads();
  int tid = threadIdx.x;
  if (tid < 32) {
    v4f tot = red[tid] + red[32 + tid] + red[64 + tid] + red[96 + tid];
    // row layout: v4f 0..15 = channel sums, 16..31 = channel sumsq
    ((v4f*)partials)[(size_t)blockIdx.x * 32 + tid] = tot;
  }
}

// ---------------------------------------------------------------------------
// K2: reduce 3136 x 128 partials -> mean[c], rstd*gamma[c].
// ---------------------------------------------------------------------------
__global__ void __launch_bounds__(1024)
k2_finalize(const float* __restrict__ partials, const float* __restrict__ gamma,
            float* __restrict__ stats) {
  __shared__ float lds[32 * 128 + 128];
  int tid = threadIdx.x;  // 1024 threads
  int chunk = tid >> 5, qi = tid & 31;
  const float4* p4 = (const float4*)partials;
  float4 a = make_float4(0.f, 0.f, 0.f, 0.f);
#pragma unroll 7
  for (int i = chunk; i < K1BLK_; i += 32) {
    float4 v = p4[(size_t)i * 32 + qi];
    a.x += v.x; a.y += v.y; a.z += v.z; a.w += v.w;
  }
  lds[chunk * 128 + qi * 4 + 0] = a.x;
  lds[chunk * 128 + qi * 4 + 1] = a.y;
  lds[chunk * 128 + qi * 4 + 2] = a.z;
  lds[chunk * 128 + qi * 4 + 3] = a.w;
  __syncthreads();
  if (tid < 128) {
    float tot = 0.f;
#pragma unroll
    for (int ch = 0; ch < 32; ch++) tot += lds[ch * 128 + tid];
    lds[32 * 128 + tid] = tot;
  }
  __syncthreads();
  if (tid < 64) {
    float mean = lds[32 * 128 + tid] / NF_;
    float msq  = lds[32 * 128 + 64 + tid] / NF_;
    float var = msq - mean * mean;            // jnp.var (ddof=0)
    float rstdg = gamma[tid] / sqrtf(var + BN_EPS_);
    stats[tid] = mean;
    stats[64 + tid] = rstdg;
  }
}

// ---------------------------------------------------------------------------
// K3: conv16 + clamp + BN affine + clamp + ReLU + real expmap0 (+projx) + store.
// 4 lanes/pixel; norms via 2 shfl_xor; stores 4x16B/lane = 4KB/wave contiguous.
// ---------------------------------------------------------------------------
__global__ void __launch_bounds__(256)
k3_final(const float4* __restrict__ u0p, const float* __restrict__ wgt,
         const float* __restrict__ bias, const float* __restrict__ stats,
         const float* __restrict__ beta, float* __restrict__ out) {
  int g = blockIdx.x * 256 + threadIdx.x;
  int qt = g & 3;
  int pix = g >> 2;
  v4f a0, a1, a2, a3;
  conv16_clamp(u0p, (const v4f*)wgt, (const v4f*)bias, pix, qt, a0, a1, a2, a3);
  const v4f* mean4 = (const v4f*)stats;
  const v4f* rg4   = (const v4f*)(stats + 64);
  const v4f* beta4 = (const v4f*)beta;
  a0 = (a0 - mean4[qt * 4 + 0]) * rg4[qt * 4 + 0] + beta4[qt * 4 + 0];
  a1 = (a1 - mean4[qt * 4 + 1]) * rg4[qt * 4 + 1] + beta4[qt * 4 + 1];
  a2 = (a2 - mean4[qt * 4 + 2]) * rg4[qt * 4 + 2] + beta4[qt * 4 + 2];
  a3 = (a3 - mean4[qt * 4 + 3]) * rg4[qt * 4 + 3] + beta4[qt * 4 + 3];
  float nv2 = hadd(a0 * a0 + a1 * a1 + a2 * a2 + a3 * a3);
  nv2 += __shfl_xor(nv2, 1, 64);
  nv2 += __shfl_xor(nv2, 2, 64);
  float nv = sqrtf(nv2);
  float sv = (nv > LCLAMP_) ? (LCLAMP_ / nv) : 1.0f;  // logmap0(expmap0(v)) fused
  a0 = vmax0(a0 * sv); a1 = vmax0(a1 * sv);
  a2 = vmax0(a2 * sv); a3 = vmax0(a3 * sv);
  float nw2 = hadd(a0 * a0 + a1 * a1 + a2 * a2 + a3 * a3);
  nw2 += __shfl_xor(nw2, 1, 64);
  nw2 += __shfl_xor(nw2, 2, 64);
  float nw = fmaxf(sqrtf(nw2), MINN_);
  float th = tanhf(nw);
  float fs = (th / nw) * fminf(1.0f, MAXNORM_ / fmaxf(th, MINN_));
  v4f* op = (v4f*)out + (size_t)pix * 16 + qt * 4;
  op[0] = a0 * fs; op[1] = a1 * fs; op[2] = a2 * fs; op[3] = a3 * fs;
}

// ---------------------------------------------------------------------------
extern "C" void kernel_launch(void* const* d_in, const int* in_sizes, int n_in,
                              void* d_out, int out_size, void* d_ws, size_t ws_size,
                              hipStream_t stream) {
  const float* x     = (const float*)d_in[0];  // [16,3,224,224]
  const float* wgt   = (const float*)d_in[1];  // [3,3,3,64] HWIO
  const float* bias  = (const float*)d_in[2];  // [64]
  const float* gamma = (const float*)d_in[3];  // [64]
  const float* beta  = (const float*)d_in[4];  // [64]
  float* out = (float*)d_out;                  // [16,224,224,64]

  char* ws = (char*)d_ws;
  float4* u0p      = (float4*)ws;                                            // 13,075,456 B
  float*  partials = (float*)(ws + (size_t)NPAD_ * 16);                      //  1,605,632 B
  float*  stats    = (float*)(ws + (size_t)NPAD_ * 16 + (size_t)K1BLK_ * 128 * 4); // 512 B

  hipLaunchKernelGGL(k0_transform, dim3((NPAD_ + 255) / 256), dim3(256), 0, stream, x, u0p);
  hipLaunchKernelGGL(k1_stats,     dim3(K1BLK_),              dim3(256), 0, stream, u0p, wgt, bias, partials);
  hipLaunchKernelGGL(k2_finalize,  dim3(1),                   dim3(1024), 0, stream, partials, gamma, stats);
  hipLaunchKernelGGL(k3_final,     dim3(K3BLK_),              dim3(256), 0, stream, u0p, wgt, bias, stats, beta, out);
}